// Round 6
// baseline (249.609 us; speedup 1.0000x reference)
//
#include <hip/hip_runtime.h>
#include <hip/hip_bf16.h>

#define NROWS 4096
#define NLAB  2048
#define NPAIR 2048

typedef __attribute__((ext_vector_type(8))) short short8;
typedef __attribute__((ext_vector_type(8))) unsigned short ushort8;
typedef __attribute__((ext_vector_type(4))) float f32x4;

__device__ __forceinline__ unsigned short f2bf(float x) {
  unsigned int u = __float_as_uint(x);
  unsigned int r = u + 0x7fffu + ((u >> 16) & 1u);   // RNE, no NaN in data
  return (unsigned short)(r >> 16);
}
__device__ __forceinline__ float bf2f(unsigned short h) {
  return __uint_as_float(((unsigned int)h) << 16);
}

// ---- fused prep: blocks [0,1024) rank/pl2/ssorted2; [1024,2048) bf16-conv + norms ----
__global__ __launch_bounds__(256) void prep_kernel(const float* __restrict__ labels,
                                                   const float* __restrict__ z1,
                                                   const float* __restrict__ z2,
                                                   int* __restrict__ rankv,
                                                   int* __restrict__ pl2v,
                                                   float* __restrict__ ssorted2,
                                                   unsigned short* __restrict__ Fb,
                                                   float* __restrict__ rout) {
  __shared__ float L[NLAB];
  const int tid = threadIdx.x;
  const int lane = tid & 63, wid = tid >> 6;
  if (blockIdx.x < 1024) {
    for (int t = tid; t < NLAB; t += 256) L[t] = labels[t];
    __syncthreads();
    const int i = blockIdx.x * 4 + wid;            // element in [0,4096)
    const float a = L[i & (NLAB - 1)];
    int combo = 0;                                  // cnt | cntLE<<13
    #pragma unroll 4
    for (int jj = 0; jj < NLAB / 64; ++jj) {
      const int j = jj * 64 + lane;
      const float l = L[j];
      if (l < a) combo += 2 + (2 << 13);
      else if (l == a) combo += ((j < i) + (j + NLAB < i)) + (2 << 13);
    }
    #pragma unroll
    for (int off = 32; off > 0; off >>= 1) combo += __shfl_down(combo, off, 64);
    if (lane == 0) {
      const int cnt = combo & 8191, cle = combo >> 13;
      rankv[i] = cnt;
      pl2v[i] = (cle >> 1) - 1;                     // last pair p with s2[p] <= a
      if (!(cnt & 1)) ssorted2[cnt >> 1] = a;       // even rank -> pair representative
    }
  } else {
    const int row = (blockIdx.x - 1024) * 4 + wid;
    const float* src = (row < NLAB) ? (z1 + (size_t)row * 256)
                                    : (z2 + (size_t)(row - NLAB) * 256);
    float4 v = ((const float4*)src)[lane];
    ushort4 o;
    o.x = f2bf(v.x); o.y = f2bf(v.y); o.z = f2bf(v.z); o.w = f2bf(v.w);
    ((ushort4*)Fb)[(size_t)row * 64 + lane] = o;
    float ss = v.x * v.x + v.y * v.y + v.z * v.z + v.w * v.w;
    #pragma unroll
    for (int off = 32; off > 0; off >>= 1) ss += __shfl_down(ss, off, 64);
    if (lane == 0) rout[row] = ss;
  }
}

// ---- G = F * F^T -> bf16, LDS-staged coalesced stores (unchanged from R5) ----
__global__ __launch_bounds__(256) void gemm_kernel(const unsigned short* __restrict__ Fb,
                                                   unsigned short* __restrict__ Gslab,
                                                   int row0) {
  __shared__ unsigned short tile[64][66];
  const int tid = threadIdx.x;
  const int lane = tid & 63, wid = tid >> 6;
  const int wm = wid >> 1, wn = wid & 1;            // 4 waves -> 2x2 of 32x32
  const int m0 = row0 + blockIdx.x * 64 + wm * 32;
  const int n0 = blockIdx.y * 64 + wn * 32;
  const int r16 = lane & 15, kg = lane >> 4;
  const f32x4 z = {0.f, 0.f, 0.f, 0.f};
  f32x4 acc00 = z, acc01 = z, acc10 = z, acc11 = z;
  const unsigned short* pa0 = Fb + (size_t)(m0 + r16) * 256 + kg * 8;
  const unsigned short* pa1 = pa0 + 16 * 256;
  const unsigned short* pb0 = Fb + (size_t)(n0 + r16) * 256 + kg * 8;
  const unsigned short* pb1 = pb0 + 16 * 256;
  #pragma unroll
  for (int ks = 0; ks < 8; ++ks) {                  // K = 256 = 8 x 32
    const int k0 = ks * 32;
    short8 a0 = *(const short8*)(pa0 + k0);
    short8 a1 = *(const short8*)(pa1 + k0);
    short8 b0 = *(const short8*)(pb0 + k0);
    short8 b1 = *(const short8*)(pb1 + k0);
    acc00 = __builtin_amdgcn_mfma_f32_16x16x32_bf16(a0, b0, acc00, 0, 0, 0);
    acc01 = __builtin_amdgcn_mfma_f32_16x16x32_bf16(a0, b1, acc01, 0, 0, 0);
    acc10 = __builtin_amdgcn_mfma_f32_16x16x32_bf16(a1, b0, acc10, 0, 0, 0);
    acc11 = __builtin_amdgcn_mfma_f32_16x16x32_bf16(a1, b1, acc11, 0, 0, 0);
  }
  // C/D layout (m89-verified): col = lane&15, row = (lane>>4)*4 + reg
  const int lr = wm * 32 + kg * 4, lc = wn * 32 + r16;
  #pragma unroll
  for (int rr = 0; rr < 4; ++rr) {
    tile[lr + rr][lc]           = f2bf(acc00[rr]);
    tile[lr + rr][lc + 16]      = f2bf(acc01[rr]);
    tile[lr + 16 + rr][lc]      = f2bf(acc10[rr]);
    tile[lr + 16 + rr][lc + 16] = f2bf(acc11[rr]);
  }
  __syncthreads();
  const int lm = blockIdx.x * 64;
  const int gcol = blockIdx.y * 64 + (tid & 7) * 8;
  #pragma unroll
  for (int k = 0; k < 2; ++k) {
    const int row = k * 32 + (tid >> 3);
    ushort8 v = *(const ushort8*)&tile[row][(tid & 7) * 8];
    *(ushort8*)(Gslab + (size_t)(lm + row) * NROWS + gcol) = v;
  }
}

// ---- paired main: rows (ia, ia+2048) share label/search structure; per pair p:
//      den = Ptot - W, W_left = P2[rR-1]-P2[p], W_right = P2[p-1]-P2[qL];
//      opposite pointer monotone over the thread's 4 consecutive pairs ----
__global__ __launch_bounds__(512, 8) void main_kernel(const unsigned short* __restrict__ Ga,
                                                      const unsigned short* __restrict__ Gbm,
                                                      const float* __restrict__ r,
                                                      const float* __restrict__ labels,
                                                      const float* __restrict__ ssorted2,
                                                      const int* __restrict__ rankv,
                                                      const int* __restrict__ pl2v,
                                                      int pair0, float2* __restrict__ part) {
  __shared__ float s2[NPAIR];                       // pair label values
  __shared__ float2 P2[NPAIR];                      // interleaved (rowA,rowB) pair sums
  __shared__ float2 wsum[8];
  __shared__ float4 red[8];
  const int tid = threadIdx.x;
  const int ia = pair0 + blockIdx.x;                // ia in [0,2048)
  const int ib = ia + NLAB;
  // phase 0: load s2, zero P2
  *(float4*)&s2[tid * 4] = ((const float4*)ssorted2)[tid];
  const float4 z4 = make_float4(0.f, 0.f, 0.f, 0.f);
  ((float4*)P2)[tid * 2] = z4;
  ((float4*)P2)[tid * 2 + 1] = z4;
  const float a = labels[ia];
  const float ra = r[ia], rb = r[ib];
  const int pL2 = pl2v[ia];                         // block-uniform
  __syncthreads();
  // pass 1: both rows' weights -> interleaved pair bins (ds atomics)
  float loA = 0.f, loB = 0.f;
  {
    const ushort8 gva = ((const ushort8*)(Ga + (size_t)blockIdx.x * NROWS))[tid];
    const ushort8 gvb = ((const ushort8*)(Gbm + (size_t)blockIdx.x * NROWS))[tid];
    const float4 rt0 = ((const float4*)r)[tid * 2];
    const float4 rt1 = ((const float4*)r)[tid * 2 + 1];
    const int4 rk0 = ((const int4*)rankv)[tid * 2];
    const int4 rk1 = ((const int4*)rankv)[tid * 2 + 1];
    const int t = tid * 8;
    float* P2f = (float*)P2;
    #define DOW(U, RT, RK) { \
      float* bp = &P2f[(RK >> 1) * 2]; \
      if (t + U != ia) { \
        float lo = -0.5f * __builtin_amdgcn_sqrtf(fmaxf(ra + RT - 2.f * bf2f(gva[U]), 0.f)); \
        loA += lo; atomicAdd(bp, __expf(lo)); } \
      if (t + U != ib) { \
        float lo = -0.5f * __builtin_amdgcn_sqrtf(fmaxf(rb + RT - 2.f * bf2f(gvb[U]), 0.f)); \
        loB += lo; atomicAdd(bp + 1, __expf(lo)); } }
    DOW(0, rt0.x, rk0.x) DOW(1, rt0.y, rk0.y) DOW(2, rt0.z, rk0.z) DOW(3, rt0.w, rk0.w)
    DOW(4, rt1.x, rk1.x) DOW(5, rt1.y, rk1.y) DOW(6, rt1.z, rk1.z) DOW(7, rt1.w, rk1.w)
    #undef DOW
  }
  __syncthreads();
  // dual inclusive prefix over 2048 pairs, 4 pairs/thread (vectorized)
  const float4 q0 = ((const float4*)P2)[tid * 2];      // (a0,b0,a1,b1)
  const float4 q1 = ((const float4*)P2)[tid * 2 + 1];  // (a2,b2,a3,b3)
  const float ca0 = q0.x,       cb0 = q0.y;
  const float ca1 = ca0 + q0.z, cb1 = cb0 + q0.w;
  const float ca2 = ca1 + q1.x, cb2 = cb1 + q1.y;
  const float ca3 = ca2 + q1.z, cb3 = cb2 + q1.w;
  const int lane = tid & 63, wid = tid >> 6;
  float xa = ca3, xb = cb3;
  #pragma unroll
  for (int off = 1; off < 64; off <<= 1) {
    float ya = __shfl_up(xa, off, 64);
    float yb = __shfl_up(xb, off, 64);
    if (lane >= off) { xa += ya; xb += yb; }
  }
  if (lane == 63) wsum[wid] = make_float2(xa, xb);
  __syncthreads();
  float woffA = 0.f, woffB = 0.f, PtotA = 0.f, PtotB = 0.f;
  #pragma unroll
  for (int w = 0; w < 8; ++w) {
    float2 ws = wsum[w];
    PtotA += ws.x; PtotB += ws.y;
    if (w < wid) { woffA += ws.x; woffB += ws.y; }
  }
  const float exclA = woffA + xa - ca3, exclB = woffB + xb - cb3;
  const float PA0 = exclA + ca0, PA1 = exclA + ca1, PA2 = exclA + ca2, PA3 = exclA + ca3;
  const float PB0 = exclB + cb0, PB1 = exclB + cb1, PB2 = exclB + cb2, PB3 = exclB + cb3;
  ((float4*)P2)[tid * 2]     = make_float4(PA0, PB0, PA1, PB1);
  ((float4*)P2)[tid * 2 + 1] = make_float4(PA2, PB2, PA3, PB3);
  __syncthreads();
  // pass 2: 4 consecutive pairs; one opposite-pointer per side, monotone decrements
  const int p0 = tid * 4;
  const float4 s2o = *(const float4*)&s2[p0];
  int rR = -1;                                      // left-side opposite ptr (lazy init)
  int qL = -1; bool qInit = false;                  // right-side opposite ptr
  float prodA = 1.f, prodB = 1.f;
  #define STEP(U, SV, INCA, INCB, PRVA, PRVB) { \
    const int p = p0 + U; \
    float WA, WB; \
    if (p <= pL2) { \
      const float v = a - SV; \
      if (rR < 0) { int lo = pL2 + 1, hi = NPAIR; \
        while (lo < hi) { int m = (lo + hi) >> 1; \
          if (s2[m] - a >= v) hi = m; else lo = m + 1; } rR = lo; } \
      else { while (rR > pL2 + 1 && s2[rR - 1] - a >= v) --rR; } \
      const float2 Pq = P2[rR - 1]; \
      WA = Pq.x - INCA; WB = Pq.y - INCB; \
    } else { \
      const float v = SV - a; \
      if (!qInit) { int lo = 0, hi = pL2 + 1; \
        while (lo < hi) { int m = (lo + hi) >> 1; \
          if (a - s2[m] >= v) lo = m + 1; else hi = m; } qL = lo - 1; qInit = true; } \
      else { while (qL >= 0 && a - s2[qL] < v) --qL; } \
      const float2 Pq = (qL >= 0) ? P2[qL] : make_float2(0.f, 0.f); \
      WA = PRVA - Pq.x; WB = PRVB - Pq.y; \
    } \
    prodA *= (PtotA - WA); prodB *= (PtotB - WB); }
  STEP(0, s2o.x, PA0, PB0, exclA, exclB)
  STEP(1, s2o.y, PA1, PB1, PA0, PB0)
  STEP(2, s2o.z, PA2, PB2, PA1, PB1)
  STEP(3, s2o.w, PA3, PB3, PA2, PB2)
  #undef STEP
  float ldA = __logf(prodA), ldB = __logf(prodB);
  // block reduce 4 values -> per-row partials
  #pragma unroll
  for (int off = 32; off > 0; off >>= 1) {
    loA += __shfl_down(loA, off, 64);
    loB += __shfl_down(loB, off, 64);
    ldA += __shfl_down(ldA, off, 64);
    ldB += __shfl_down(ldB, off, 64);
  }
  if (lane == 0) red[wid] = make_float4(loA, ldA, loB, ldB);
  __syncthreads();
  if (tid == 0) {
    float LA = 0.f, DA = 0.f, LB = 0.f, DB = 0.f;
    #pragma unroll
    for (int w = 0; w < 8; ++w) {
      float4 q = red[w];
      LA += q.x; DA += q.y; LB += q.z; DB += q.w;
    }
    part[ia] = make_float2(LA, 2.f * DA - __logf(PtotA));
    part[ib] = make_float2(LB, 2.f * DB - __logf(PtotB));
  }
}

__global__ __launch_bounds__(512) void final_kernel(const float2* __restrict__ part,
                                                    float* __restrict__ out) {
  const int tid = threadIdx.x;
  double L = 0.0, D = 0.0;
  for (int t = tid; t < NROWS; t += 512) {
    float2 p = part[t];
    L += (double)p.x; D += (double)p.y;
  }
  const int lane = tid & 63, wid = tid >> 6;
  #pragma unroll
  for (int off = 32; off > 0; off >>= 1) {
    L += __shfl_down(L, off, 64);
    D += __shfl_down(D, off, 64);
  }
  __shared__ double sL[8], sD[8];
  if (lane == 0) { sL[wid] = L; sD[wid] = D; }
  __syncthreads();
  if (tid == 0) {
    double Ls = 0.0, Ds = 0.0;
    #pragma unroll
    for (int w = 0; w < 8; ++w) { Ls += sL[w]; Ds += sD[w]; }
    out[0] = (float)((Ds - Ls) / 16773120.0);       // (sum log den - sum lo)/(n(n-1))
  }
}

extern "C" void kernel_launch(void* const* d_in, const int* in_sizes, int n_in,
                              void* d_out, int out_size, void* d_ws, size_t ws_size,
                              hipStream_t stream) {
  (void)in_sizes; (void)n_in; (void)out_size;
  const float* z1     = (const float*)d_in[0];
  const float* z2     = (const float*)d_in[1];
  const float* labels = (const float*)d_in[2];
  float* out = (float*)d_out;

  char* ws = (char*)d_ws;
  float2* part           = (float2*)ws;                       // 32 KB
  float*  ssorted2       = (float*)(ws + 32768);              // 8 KB
  int*    rankv          = (int*)(ws + 40960);                // 16 KB
  float*  rbuf           = (float*)(ws + 57344);              // 16 KB
  int*    pl2v           = (int*)(ws + 73728);                // 16 KB
  unsigned short* Fb     = (unsigned short*)(ws + 131072);    // 2 MB bf16 features
  const size_t G_off = (size_t)4 << 20;
  unsigned short* G = (unsigned short*)(ws + G_off);          // bf16 G slabs (a+b)

  // pairs per iteration: each pair needs two 4096-col bf16 rows = 16 KB
  size_t pairs_cap = (ws_size > G_off + (size_t)64 * 16384)
                         ? (ws_size - G_off) / 16384 : 64;
  int R2 = (int)((pairs_cap / 64) * 64);
  if (R2 < 64) R2 = 64;
  if (R2 > NLAB) R2 = NLAB;

  prep_kernel<<<2048, 256, 0, stream>>>(labels, z1, z2, rankv, pl2v, ssorted2, Fb, rbuf);
  for (int p0 = 0; p0 < NLAB; p0 += R2) {
    int rows = NLAB - p0; if (rows > R2) rows = R2;
    unsigned short* Gb = G + (size_t)rows * NROWS;
    gemm_kernel<<<dim3(rows / 64, NROWS / 64), 256, 0, stream>>>(Fb, G, p0);
    gemm_kernel<<<dim3(rows / 64, NROWS / 64), 256, 0, stream>>>(Fb, Gb, NLAB + p0);
    main_kernel<<<rows, 512, 0, stream>>>(G, Gb, rbuf, labels, ssorted2, rankv, pl2v,
                                          p0, part);
  }
  final_kernel<<<1, 512, 0, stream>>>(part, out);
}

// Round 7
// 157.844 us; speedup vs baseline: 1.5814x; 1.5814x over previous
//
#include <hip/hip_runtime.h>
#include <hip/hip_bf16.h>

#define NROWS 4096
#define NLAB  2048
#define NPAIR 2048
#define FMAXV 3.402823466e+38f

typedef __attribute__((ext_vector_type(8))) short short8;
typedef __attribute__((ext_vector_type(8))) unsigned short ushort8;
typedef __attribute__((ext_vector_type(4))) float f32x4;

__device__ __forceinline__ unsigned short f2bf(float x) {
  unsigned int u = __float_as_uint(x);
  unsigned int r = u + 0x7fffu + ((u >> 16) & 1u);   // RNE, no NaN in data
  return (unsigned short)(r >> 16);
}
__device__ __forceinline__ float bf2f(unsigned short h) {
  return __uint_as_float(((unsigned int)h) << 16);
}

// ---- fused prep (1024 blocks x 256): per wave = one original row:
//      rank by counting sort, then write bf16 feature row + norm at SORTED slot ----
__global__ __launch_bounds__(256) void prep_kernel(const float* __restrict__ labels,
                                                   const float* __restrict__ z1,
                                                   const float* __restrict__ z2,
                                                   unsigned short* __restrict__ Fb,
                                                   float* __restrict__ rs,
                                                   float* __restrict__ ssorted2,
                                                   int* __restrict__ pl2v) {
  __shared__ float L[NLAB];
  const int tid = threadIdx.x;
  const int lane = tid & 63, wid = tid >> 6;
  for (int t = tid; t < NLAB; t += 256) L[t] = labels[t];
  __syncthreads();
  const int i = blockIdx.x * 4 + wid;               // original row in [0,4096)
  const float a = L[i & (NLAB - 1)];
  int combo = 0;                                     // cnt | cntLE<<13
  #pragma unroll 4
  for (int jj = 0; jj < NLAB / 64; ++jj) {
    const int j = jj * 64 + lane;
    const float l = L[j];
    if (l < a) combo += 2 + (2 << 13);
    else if (l == a) combo += ((j < i) + (j + NLAB < i)) + (2 << 13);
  }
  #pragma unroll
  for (int off = 32; off > 0; off >>= 1) combo += __shfl_down(combo, off, 64);
  combo = __shfl(combo, 0, 64);                      // broadcast rank to wave
  const int cnt = combo & 8191, cle = combo >> 13;
  // feature row -> bf16 at sorted slot cnt; norm alongside
  const float* src = (i < NLAB) ? (z1 + (size_t)i * 256)
                                : (z2 + (size_t)(i - NLAB) * 256);
  float4 v = ((const float4*)src)[lane];
  ushort4 o;
  o.x = f2bf(v.x); o.y = f2bf(v.y); o.z = f2bf(v.z); o.w = f2bf(v.w);
  ((ushort4*)Fb)[(size_t)cnt * 64 + lane] = o;
  float ss = v.x * v.x + v.y * v.y + v.z * v.z + v.w * v.w;
  #pragma unroll
  for (int off = 32; off > 0; off >>= 1) ss += __shfl_down(ss, off, 64);
  if (lane == 0) {
    rs[cnt] = ss;
    if (!(cnt & 1)) {                                // even rank: pair representative
      ssorted2[cnt >> 1] = a;
      pl2v[cnt >> 1] = (cle >> 1) - 1;               // last pair p with s2[p] <= a
    }
  }
}

// ---- G = F_sorted * F_sorted^T -> bf16, LDS-staged coalesced stores ----
__global__ __launch_bounds__(256) void gemm_kernel(const unsigned short* __restrict__ Fb,
                                                   unsigned short* __restrict__ Gslab,
                                                   int row0) {
  __shared__ unsigned short tile[64][66];
  const int tid = threadIdx.x;
  const int lane = tid & 63, wid = tid >> 6;
  const int wm = wid >> 1, wn = wid & 1;            // 4 waves -> 2x2 of 32x32
  const int m0 = row0 + blockIdx.x * 64 + wm * 32;
  const int n0 = blockIdx.y * 64 + wn * 32;
  const int r16 = lane & 15, kg = lane >> 4;
  const f32x4 z = {0.f, 0.f, 0.f, 0.f};
  f32x4 acc00 = z, acc01 = z, acc10 = z, acc11 = z;
  const unsigned short* pa0 = Fb + (size_t)(m0 + r16) * 256 + kg * 8;
  const unsigned short* pa1 = pa0 + 16 * 256;
  const unsigned short* pb0 = Fb + (size_t)(n0 + r16) * 256 + kg * 8;
  const unsigned short* pb1 = pb0 + 16 * 256;
  #pragma unroll
  for (int ks = 0; ks < 8; ++ks) {                  // K = 256 = 8 x 32
    const int k0 = ks * 32;
    short8 a0 = *(const short8*)(pa0 + k0);
    short8 a1 = *(const short8*)(pa1 + k0);
    short8 b0 = *(const short8*)(pb0 + k0);
    short8 b1 = *(const short8*)(pb1 + k0);
    acc00 = __builtin_amdgcn_mfma_f32_16x16x32_bf16(a0, b0, acc00, 0, 0, 0);
    acc01 = __builtin_amdgcn_mfma_f32_16x16x32_bf16(a0, b1, acc01, 0, 0, 0);
    acc10 = __builtin_amdgcn_mfma_f32_16x16x32_bf16(a1, b0, acc10, 0, 0, 0);
    acc11 = __builtin_amdgcn_mfma_f32_16x16x32_bf16(a1, b1, acc11, 0, 0, 0);
  }
  // C/D layout (m89-verified): col = lane&15, row = (lane>>4)*4 + reg
  const int lr = wm * 32 + kg * 4, lc = wn * 32 + r16;
  #pragma unroll
  for (int rr = 0; rr < 4; ++rr) {
    tile[lr + rr][lc]           = f2bf(acc00[rr]);
    tile[lr + rr][lc + 16]      = f2bf(acc01[rr]);
    tile[lr + 16 + rr][lc]      = f2bf(acc10[rr]);
    tile[lr + 16 + rr][lc + 16] = f2bf(acc11[rr]);
  }
  __syncthreads();
  const int lm = blockIdx.x * 64;
  const int gcol = blockIdx.y * 64 + (tid & 7) * 8;
  #pragma unroll
  for (int k = 0; k < 2; ++k) {
    const int row = k * 32 + (tid >> 3);
    ushort8 v = *(const ushort8*)&tile[row][(tid & 7) * 8];
    *(ushort8*)(Gslab + (size_t)(lm + row) * NROWS + gcol) = v;
  }
}

// ---- main: block = sorted pair jj (rows 2jj, 2jj+1). G sorted -> sequential
//      weights, register pair-compress + prefix, NO LDS scatter/atomics ----
__global__ __launch_bounds__(512, 8) void main_kernel(const unsigned short* __restrict__ G,
                                                      const float* __restrict__ rs,
                                                      const float* __restrict__ ssorted2,
                                                      const int* __restrict__ pl2v,
                                                      int pair0, float2* __restrict__ part) {
  __shared__ float s2[NPAIR];                       // pair label values
  __shared__ float2 P2[NPAIR];                      // interleaved (A,B) pair prefix sums
  __shared__ float2 wsum[8];
  __shared__ float4 red[8];
  const int tid = threadIdx.x;
  const int jj = pair0 + blockIdx.x;                // pair index in [0,2048)
  const int mA = 2 * jj, mB = mA + 1;               // sorted row slots
  *(float4*)&s2[tid * 4] = ((const float4*)ssorted2)[tid];
  const float a = ssorted2[jj];
  const float ra = rs[mA], rb = rs[mB];
  const int pL2 = pl2v[jj];                         // block-uniform
  // pass 1: sequential weights for both rows (slab-local G rows 2bx, 2bx+1)
  float loA = 0.f, loB = 0.f;
  float wA0, wA1, wA2, wA3, wA4, wA5, wA6, wA7;
  float wB0, wB1, wB2, wB3, wB4, wB5, wB6, wB7;
  {
    const ushort8 gva = ((const ushort8*)(G + (size_t)(2 * blockIdx.x) * NROWS))[tid];
    const ushort8 gvb = ((const ushort8*)(G + (size_t)(2 * blockIdx.x + 1) * NROWS))[tid];
    const float4 rt0 = ((const float4*)rs)[tid * 2];
    const float4 rt1 = ((const float4*)rs)[tid * 2 + 1];
    const int t = tid * 8;
    #define DOW(U, RT, WA, WB) { \
      WA = 0.f; WB = 0.f; \
      if (t + U != mA) { \
        float lo = -0.5f * __builtin_amdgcn_sqrtf(fmaxf(ra + RT - 2.f * bf2f(gva[U]), 0.f)); \
        loA += lo; WA = __expf(lo); } \
      if (t + U != mB) { \
        float lo = -0.5f * __builtin_amdgcn_sqrtf(fmaxf(rb + RT - 2.f * bf2f(gvb[U]), 0.f)); \
        loB += lo; WB = __expf(lo); } }
    DOW(0, rt0.x, wA0, wB0) DOW(1, rt0.y, wA1, wB1)
    DOW(2, rt0.z, wA2, wB2) DOW(3, rt0.w, wA3, wB3)
    DOW(4, rt1.x, wA4, wB4) DOW(5, rt1.y, wA5, wB5)
    DOW(6, rt1.z, wA6, wB6) DOW(7, rt1.w, wA7, wB7)
    #undef DOW
  }
  // register pair-compress (slots are consecutive: pairs pb..pb+3) + local prefix
  const float ca0 = wA0 + wA1, cb0 = wB0 + wB1;
  const float ca1 = ca0 + wA2 + wA3, cb1 = cb0 + wB2 + wB3;
  const float ca2 = ca1 + wA4 + wA5, cb2 = cb1 + wB4 + wB5;
  const float ca3 = ca2 + wA6 + wA7, cb3 = cb2 + wB6 + wB7;
  const int lane = tid & 63, wid = tid >> 6;
  float xa = ca3, xb = cb3;
  #pragma unroll
  for (int off = 1; off < 64; off <<= 1) {
    float ya = __shfl_up(xa, off, 64);
    float yb = __shfl_up(xb, off, 64);
    if (lane >= off) { xa += ya; xb += yb; }
  }
  if (lane == 63) wsum[wid] = make_float2(xa, xb);
  __syncthreads();
  float woffA = 0.f, woffB = 0.f, PtotA = 0.f, PtotB = 0.f;
  #pragma unroll
  for (int w = 0; w < 8; ++w) {
    float2 ws = wsum[w];
    PtotA += ws.x; PtotB += ws.y;
    if (w < wid) { woffA += ws.x; woffB += ws.y; }
  }
  const float exclA = woffA + xa - ca3, exclB = woffB + xb - cb3;
  const float PA0 = exclA + ca0, PA1 = exclA + ca1, PA2 = exclA + ca2, PA3 = exclA + ca3;
  const float PB0 = exclB + cb0, PB1 = exclB + cb1, PB2 = exclB + cb2, PB3 = exclB + cb3;
  const int pb = tid * 4;
  ((float4*)P2)[tid * 2]     = make_float4(PA0, PB0, PA1, PB1);
  ((float4*)P2)[tid * 2 + 1] = make_float4(PA2, PB2, PA3, PB3);
  __syncthreads();
  // pass 2: 4 consecutive pairs; lazy-init opposite pointer + monotone decrements
  const float4 s2o = *(const float4*)&s2[pb];
  int rR = -1;
  int qL = -1; bool qInit = false;
  float prodA = 1.f, prodB = 1.f;
  #define STEP(U, SV, INCA, INCB, PRVA, PRVB) { \
    const int p = pb + U; \
    float WA, WB; \
    if (p <= pL2) { \
      const float v = a - SV; \
      if (rR < 0) { int lo = pL2 + 1, hi = NPAIR; \
        while (lo < hi) { int m = (lo + hi) >> 1; \
          if (s2[m] - a >= v) hi = m; else lo = m + 1; } rR = lo; } \
      else { while (rR > pL2 + 1 && s2[rR - 1] - a >= v) --rR; } \
      const float2 Pq = P2[rR - 1]; \
      WA = Pq.x - INCA; WB = Pq.y - INCB; \
    } else { \
      const float v = SV - a; \
      if (!qInit) { int lo = 0, hi = pL2 + 1; \
        while (lo < hi) { int m = (lo + hi) >> 1; \
          if (a - s2[m] >= v) lo = m + 1; else hi = m; } qL = lo - 1; qInit = true; } \
      else { while (qL >= 0 && a - s2[qL] < v) --qL; } \
      const float2 Pq = (qL >= 0) ? P2[qL] : make_float2(0.f, 0.f); \
      WA = PRVA - Pq.x; WB = PRVB - Pq.y; \
    } \
    prodA *= (PtotA - WA); prodB *= (PtotB - WB); }
  STEP(0, s2o.x, PA0, PB0, exclA, exclB)
  STEP(1, s2o.y, PA1, PB1, PA0, PB0)
  STEP(2, s2o.z, PA2, PB2, PA1, PB1)
  STEP(3, s2o.w, PA3, PB3, PA2, PB2)
  #undef STEP
  float ldA = __logf(prodA), ldB = __logf(prodB);
  // block reduce -> per-row partials
  #pragma unroll
  for (int off = 32; off > 0; off >>= 1) {
    loA += __shfl_down(loA, off, 64);
    loB += __shfl_down(loB, off, 64);
    ldA += __shfl_down(ldA, off, 64);
    ldB += __shfl_down(ldB, off, 64);
  }
  if (lane == 0) red[wid] = make_float4(loA, ldA, loB, ldB);
  __syncthreads();
  if (tid == 0) {
    float LA = 0.f, DA = 0.f, LB = 0.f, DB = 0.f;
    #pragma unroll
    for (int w = 0; w < 8; ++w) {
      float4 q = red[w];
      LA += q.x; DA += q.y; LB += q.z; DB += q.w;
    }
    part[mA] = make_float2(LA, 2.f * DA - __logf(PtotA));
    part[mB] = make_float2(LB, 2.f * DB - __logf(PtotB));
  }
}

__global__ __launch_bounds__(512) void final_kernel(const float2* __restrict__ part,
                                                    float* __restrict__ out) {
  const int tid = threadIdx.x;
  double L = 0.0, D = 0.0;
  for (int t = tid; t < NROWS; t += 512) {
    float2 p = part[t];
    L += (double)p.x; D += (double)p.y;
  }
  const int lane = tid & 63, wid = tid >> 6;
  #pragma unroll
  for (int off = 32; off > 0; off >>= 1) {
    L += __shfl_down(L, off, 64);
    D += __shfl_down(D, off, 64);
  }
  __shared__ double sL[8], sD[8];
  if (lane == 0) { sL[wid] = L; sD[wid] = D; }
  __syncthreads();
  if (tid == 0) {
    double Ls = 0.0, Ds = 0.0;
    #pragma unroll
    for (int w = 0; w < 8; ++w) { Ls += sL[w]; Ds += sD[w]; }
    out[0] = (float)((Ds - Ls) / 16773120.0);       // (sum log den - sum lo)/(n(n-1))
  }
}

extern "C" void kernel_launch(void* const* d_in, const int* in_sizes, int n_in,
                              void* d_out, int out_size, void* d_ws, size_t ws_size,
                              hipStream_t stream) {
  (void)in_sizes; (void)n_in; (void)out_size;
  const float* z1     = (const float*)d_in[0];
  const float* z2     = (const float*)d_in[1];
  const float* labels = (const float*)d_in[2];
  float* out = (float*)d_out;

  char* ws = (char*)d_ws;
  float2* part           = (float2*)ws;                       // 32 KB
  float*  ssorted2       = (float*)(ws + 32768);              // 8 KB
  float*  rs             = (float*)(ws + 40960);              // 16 KB (sorted norms)
  int*    pl2v           = (int*)(ws + 57344);                // 8 KB
  unsigned short* Fb     = (unsigned short*)(ws + 131072);    // 2 MB bf16 sorted feats
  const size_t G_off = (size_t)4 << 20;
  unsigned short* G = (unsigned short*)(ws + G_off);          // bf16 sorted Gram

  // pairs per slab: each pair = two 4096-col bf16 rows = 16 KB
  size_t pairs_cap = (ws_size > G_off + (size_t)64 * 16384)
                         ? (ws_size - G_off) / 16384 : 64;
  int R2 = (int)((pairs_cap / 64) * 64);
  if (R2 < 64) R2 = 64;
  if (R2 > NLAB) R2 = NLAB;

  prep_kernel<<<1024, 256, 0, stream>>>(labels, z1, z2, Fb, rs, ssorted2, pl2v);
  for (int p0 = 0; p0 < NLAB; p0 += R2) {
    int pairs = NLAB - p0; if (pairs > R2) pairs = R2;
    gemm_kernel<<<dim3(pairs * 2 / 64, NROWS / 64), 256, 0, stream>>>(Fb, G, 2 * p0);
    main_kernel<<<pairs, 512, 0, stream>>>(G, rs, ssorted2, pl2v, p0, part);
  }
  final_kernel<<<1, 512, 0, stream>>>(part, out);
}

// Round 8
// 131.229 us; speedup vs baseline: 1.9021x; 1.2028x over previous
//
#include <hip/hip_runtime.h>
#include <hip/hip_bf16.h>

#define NROWS 4096
#define NLAB  2048
#define NPAIR 2048
#define FMAXV 3.402823466e+38f

typedef __attribute__((ext_vector_type(8))) short short8;
typedef __attribute__((ext_vector_type(8))) unsigned short ushort8;
typedef __attribute__((ext_vector_type(4))) float f32x4;

__device__ __forceinline__ unsigned short f2bf(float x) {
  unsigned int u = __float_as_uint(x);
  unsigned int r = u + 0x7fffu + ((u >> 16) & 1u);   // RNE, no NaN in data
  return (unsigned short)(r >> 16);
}
__device__ __forceinline__ float bf2f(unsigned short h) {
  return __uint_as_float(((unsigned int)h) << 16);
}

// ---- fused prep (1024 blocks x 256): per wave = one original row:
//      rank by counting sort, then write bf16 feature row + norm at SORTED slot ----
__global__ __launch_bounds__(256) void prep_kernel(const float* __restrict__ labels,
                                                   const float* __restrict__ z1,
                                                   const float* __restrict__ z2,
                                                   unsigned short* __restrict__ Fb,
                                                   float* __restrict__ rs,
                                                   float* __restrict__ ssorted2,
                                                   int* __restrict__ pl2v) {
  __shared__ float L[NLAB];
  const int tid = threadIdx.x;
  const int lane = tid & 63, wid = tid >> 6;
  for (int t = tid; t < NLAB; t += 256) L[t] = labels[t];
  __syncthreads();
  const int i = blockIdx.x * 4 + wid;               // original row in [0,4096)
  const float a = L[i & (NLAB - 1)];
  int combo = 0;                                     // cnt | cntLE<<13
  #pragma unroll 4
  for (int jj = 0; jj < NLAB / 64; ++jj) {
    const int j = jj * 64 + lane;
    const float l = L[j];
    if (l < a) combo += 2 + (2 << 13);
    else if (l == a) combo += ((j < i) + (j + NLAB < i)) + (2 << 13);
  }
  #pragma unroll
  for (int off = 32; off > 0; off >>= 1) combo += __shfl_down(combo, off, 64);
  combo = __shfl(combo, 0, 64);                      // broadcast rank to wave
  const int cnt = combo & 8191, cle = combo >> 13;
  const float* src = (i < NLAB) ? (z1 + (size_t)i * 256)
                                : (z2 + (size_t)(i - NLAB) * 256);
  float4 v = ((const float4*)src)[lane];
  ushort4 o;
  o.x = f2bf(v.x); o.y = f2bf(v.y); o.z = f2bf(v.z); o.w = f2bf(v.w);
  ((ushort4*)Fb)[(size_t)cnt * 64 + lane] = o;
  float ss = v.x * v.x + v.y * v.y + v.z * v.z + v.w * v.w;
  #pragma unroll
  for (int off = 32; off > 0; off >>= 1) ss += __shfl_down(ss, off, 64);
  if (lane == 0) {
    rs[cnt] = ss;
    if (!(cnt & 1)) {                                // even rank: pair representative
      ssorted2[cnt >> 1] = a;
      pl2v[cnt >> 1] = (cle >> 1) - 1;               // last pair p with s2[p] <= a
    }
  }
}

// ---- G = F_sorted * F_sorted^T -> bf16. 128x128/block, 64x64/wave, deep ILP ----
__global__ __launch_bounds__(256, 2) void gemm_kernel(const unsigned short* __restrict__ Fb,
                                                      unsigned short* __restrict__ Gslab,
                                                      int row0) {
  __shared__ unsigned short tile[128][132];         // pad 132: bank-spread stores
  const int tid = threadIdx.x;
  const int lane = tid & 63, wid = tid >> 6;
  const int wm = wid >> 1, wn = wid & 1;            // 4 waves -> 2x2 of 64x64
  const int m0 = row0 + blockIdx.x * 128 + wm * 64;
  const int n0 = blockIdx.y * 128 + wn * 64;
  const int r16 = lane & 15, kg = lane >> 4;
  f32x4 acc[4][4];
  #pragma unroll
  for (int rg = 0; rg < 4; ++rg)
    #pragma unroll
    for (int cg = 0; cg < 4; ++cg) acc[rg][cg] = (f32x4){0.f, 0.f, 0.f, 0.f};
  const unsigned short* pa = Fb + (size_t)(m0 + r16) * 256 + kg * 8;
  const unsigned short* pb = Fb + (size_t)(n0 + r16) * 256 + kg * 8;
  #pragma unroll
  for (int ks = 0; ks < 8; ++ks) {                  // K = 256 = 8 x 32
    const int k0 = ks * 32;
    short8 a[4], b[4];
    #pragma unroll
    for (int rg = 0; rg < 4; ++rg) a[rg] = *(const short8*)(pa + rg * 16 * 256 + k0);
    #pragma unroll
    for (int cg = 0; cg < 4; ++cg) b[cg] = *(const short8*)(pb + cg * 16 * 256 + k0);
    #pragma unroll
    for (int rg = 0; rg < 4; ++rg)
      #pragma unroll
      for (int cg = 0; cg < 4; ++cg)
        acc[rg][cg] = __builtin_amdgcn_mfma_f32_16x16x32_bf16(a[rg], b[cg], acc[rg][cg], 0, 0, 0);
  }
  // C/D layout (m89-verified): A-row = (lane>>4)*4 + reg, B-col = lane&15
  #pragma unroll
  for (int rg = 0; rg < 4; ++rg)
    #pragma unroll
    for (int cg = 0; cg < 4; ++cg)
      #pragma unroll
      for (int rr = 0; rr < 4; ++rr)
        tile[wm * 64 + rg * 16 + kg * 4 + rr][wn * 64 + cg * 16 + r16] = f2bf(acc[rg][cg][rr]);
  __syncthreads();
  // coalesced stores: thread t covers 16B of a row; 16 threads/row; 8 passes
  const int lm = blockIdx.x * 128;
  const int gcol = blockIdx.y * 128 + (tid & 15) * 8;
  #pragma unroll
  for (int pass = 0; pass < 8; ++pass) {
    const int row = pass * 16 + (tid >> 4);
    ushort8 v = *(const ushort8*)&tile[row][(tid & 15) * 8];
    *(ushort8*)(Gslab + (size_t)(lm + row) * NROWS + gcol) = v;
  }
}

// ---- main: block = sorted pair jj (rows 2jj, 2jj+1). G sorted -> sequential
//      weights, register pair-compress + prefix, NO LDS scatter/atomics ----
__global__ __launch_bounds__(512, 8) void main_kernel(const unsigned short* __restrict__ G,
                                                      const float* __restrict__ rs,
                                                      const float* __restrict__ ssorted2,
                                                      const int* __restrict__ pl2v,
                                                      int pair0, float2* __restrict__ part) {
  __shared__ float s2[NPAIR];                       // pair label values
  __shared__ float2 P2[NPAIR];                      // interleaved (A,B) pair prefix sums
  __shared__ float2 wsum[8];
  __shared__ float4 red[8];
  const int tid = threadIdx.x;
  const int jj = pair0 + blockIdx.x;                // pair index in [0,2048)
  const int mA = 2 * jj, mB = mA + 1;               // sorted row slots
  *(float4*)&s2[tid * 4] = ((const float4*)ssorted2)[tid];
  const float a = ssorted2[jj];
  const float ra = rs[mA], rb = rs[mB];
  const int pL2 = pl2v[jj];                         // block-uniform
  float loA = 0.f, loB = 0.f;
  float wA0, wA1, wA2, wA3, wA4, wA5, wA6, wA7;
  float wB0, wB1, wB2, wB3, wB4, wB5, wB6, wB7;
  {
    const ushort8 gva = ((const ushort8*)(G + (size_t)(2 * blockIdx.x) * NROWS))[tid];
    const ushort8 gvb = ((const ushort8*)(G + (size_t)(2 * blockIdx.x + 1) * NROWS))[tid];
    const float4 rt0 = ((const float4*)rs)[tid * 2];
    const float4 rt1 = ((const float4*)rs)[tid * 2 + 1];
    const int t = tid * 8;
    #define DOW(U, RT, WA, WB) { \
      WA = 0.f; WB = 0.f; \
      if (t + U != mA) { \
        float lo = -0.5f * __builtin_amdgcn_sqrtf(fmaxf(ra + RT - 2.f * bf2f(gva[U]), 0.f)); \
        loA += lo; WA = __expf(lo); } \
      if (t + U != mB) { \
        float lo = -0.5f * __builtin_amdgcn_sqrtf(fmaxf(rb + RT - 2.f * bf2f(gvb[U]), 0.f)); \
        loB += lo; WB = __expf(lo); } }
    DOW(0, rt0.x, wA0, wB0) DOW(1, rt0.y, wA1, wB1)
    DOW(2, rt0.z, wA2, wB2) DOW(3, rt0.w, wA3, wB3)
    DOW(4, rt1.x, wA4, wB4) DOW(5, rt1.y, wA5, wB5)
    DOW(6, rt1.z, wA6, wB6) DOW(7, rt1.w, wA7, wB7)
    #undef DOW
  }
  const float ca0 = wA0 + wA1, cb0 = wB0 + wB1;
  const float ca1 = ca0 + wA2 + wA3, cb1 = cb0 + wB2 + wB3;
  const float ca2 = ca1 + wA4 + wA5, cb2 = cb1 + wB4 + wB5;
  const float ca3 = ca2 + wA6 + wA7, cb3 = cb2 + wB6 + wB7;
  const int lane = tid & 63, wid = tid >> 6;
  float xa = ca3, xb = cb3;
  #pragma unroll
  for (int off = 1; off < 64; off <<= 1) {
    float ya = __shfl_up(xa, off, 64);
    float yb = __shfl_up(xb, off, 64);
    if (lane >= off) { xa += ya; xb += yb; }
  }
  if (lane == 63) wsum[wid] = make_float2(xa, xb);
  __syncthreads();
  float woffA = 0.f, woffB = 0.f, PtotA = 0.f, PtotB = 0.f;
  #pragma unroll
  for (int w = 0; w < 8; ++w) {
    float2 ws = wsum[w];
    PtotA += ws.x; PtotB += ws.y;
    if (w < wid) { woffA += ws.x; woffB += ws.y; }
  }
  const float exclA = woffA + xa - ca3, exclB = woffB + xb - cb3;
  const float PA0 = exclA + ca0, PA1 = exclA + ca1, PA2 = exclA + ca2, PA3 = exclA + ca3;
  const float PB0 = exclB + cb0, PB1 = exclB + cb1, PB2 = exclB + cb2, PB3 = exclB + cb3;
  const int pb = tid * 4;
  ((float4*)P2)[tid * 2]     = make_float4(PA0, PB0, PA1, PB1);
  ((float4*)P2)[tid * 2 + 1] = make_float4(PA2, PB2, PA3, PB3);
  __syncthreads();
  const float4 s2o = *(const float4*)&s2[pb];
  int rR = -1;
  int qL = -1; bool qInit = false;
  float prodA = 1.f, prodB = 1.f;
  #define STEP(U, SV, INCA, INCB, PRVA, PRVB) { \
    const int p = pb + U; \
    float WA, WB; \
    if (p <= pL2) { \
      const float v = a - SV; \
      if (rR < 0) { int lo = pL2 + 1, hi = NPAIR; \
        while (lo < hi) { int m = (lo + hi) >> 1; \
          if (s2[m] - a >= v) hi = m; else lo = m + 1; } rR = lo; } \
      else { while (rR > pL2 + 1 && s2[rR - 1] - a >= v) --rR; } \
      const float2 Pq = P2[rR - 1]; \
      WA = Pq.x - INCA; WB = Pq.y - INCB; \
    } else { \
      const float v = SV - a; \
      if (!qInit) { int lo = 0, hi = pL2 + 1; \
        while (lo < hi) { int m = (lo + hi) >> 1; \
          if (a - s2[m] >= v) lo = m + 1; else hi = m; } qL = lo - 1; qInit = true; } \
      else { while (qL >= 0 && a - s2[qL] < v) --qL; } \
      const float2 Pq = (qL >= 0) ? P2[qL] : make_float2(0.f, 0.f); \
      WA = PRVA - Pq.x; WB = PRVB - Pq.y; \
    } \
    prodA *= (PtotA - WA); prodB *= (PtotB - WB); }
  STEP(0, s2o.x, PA0, PB0, exclA, exclB)
  STEP(1, s2o.y, PA1, PB1, PA0, PB0)
  STEP(2, s2o.z, PA2, PB2, PA1, PB1)
  STEP(3, s2o.w, PA3, PB3, PA2, PB2)
  #undef STEP
  float ldA = __logf(prodA), ldB = __logf(prodB);
  #pragma unroll
  for (int off = 32; off > 0; off >>= 1) {
    loA += __shfl_down(loA, off, 64);
    loB += __shfl_down(loB, off, 64);
    ldA += __shfl_down(ldA, off, 64);
    ldB += __shfl_down(ldB, off, 64);
  }
  if (lane == 0) red[wid] = make_float4(loA, ldA, loB, ldB);
  __syncthreads();
  if (tid == 0) {
    float LA = 0.f, DA = 0.f, LB = 0.f, DB = 0.f;
    #pragma unroll
    for (int w = 0; w < 8; ++w) {
      float4 q = red[w];
      LA += q.x; DA += q.y; LB += q.z; DB += q.w;
    }
    part[mA] = make_float2(LA, 2.f * DA - __logf(PtotA));
    part[mB] = make_float2(LB, 2.f * DB - __logf(PtotB));
  }
}

__global__ __launch_bounds__(512) void final_kernel(const float2* __restrict__ part,
                                                    float* __restrict__ out) {
  const int tid = threadIdx.x;
  double L = 0.0, D = 0.0;
  for (int t = tid; t < NROWS; t += 512) {
    float2 p = part[t];
    L += (double)p.x; D += (double)p.y;
  }
  const int lane = tid & 63, wid = tid >> 6;
  #pragma unroll
  for (int off = 32; off > 0; off >>= 1) {
    L += __shfl_down(L, off, 64);
    D += __shfl_down(D, off, 64);
  }
  __shared__ double sL[8], sD[8];
  if (lane == 0) { sL[wid] = L; sD[wid] = D; }
  __syncthreads();
  if (tid == 0) {
    double Ls = 0.0, Ds = 0.0;
    #pragma unroll
    for (int w = 0; w < 8; ++w) { Ls += sL[w]; Ds += sD[w]; }
    out[0] = (float)((Ds - Ls) / 16773120.0);       // (sum log den - sum lo)/(n(n-1))
  }
}

extern "C" void kernel_launch(void* const* d_in, const int* in_sizes, int n_in,
                              void* d_out, int out_size, void* d_ws, size_t ws_size,
                              hipStream_t stream) {
  (void)in_sizes; (void)n_in; (void)out_size;
  const float* z1     = (const float*)d_in[0];
  const float* z2     = (const float*)d_in[1];
  const float* labels = (const float*)d_in[2];
  float* out = (float*)d_out;

  char* ws = (char*)d_ws;
  float2* part           = (float2*)ws;                       // 32 KB
  float*  ssorted2       = (float*)(ws + 32768);              // 8 KB
  float*  rs             = (float*)(ws + 40960);              // 16 KB (sorted norms)
  int*    pl2v           = (int*)(ws + 57344);                // 8 KB
  unsigned short* Fb     = (unsigned short*)(ws + 131072);    // 2 MB bf16 sorted feats
  const size_t G_off = (size_t)4 << 20;
  unsigned short* G = (unsigned short*)(ws + G_off);          // bf16 sorted Gram

  // pairs per slab: each pair = two 4096-col bf16 rows = 16 KB; keep 64-pair quantum
  size_t pairs_cap = (ws_size > G_off + (size_t)64 * 16384)
                         ? (ws_size - G_off) / 16384 : 64;
  int R2 = (int)((pairs_cap / 64) * 64);
  if (R2 < 64) R2 = 64;
  if (R2 > NLAB) R2 = NLAB;

  prep_kernel<<<1024, 256, 0, stream>>>(labels, z1, z2, Fb, rs, ssorted2, pl2v);
  for (int p0 = 0; p0 < NLAB; p0 += R2) {
    int pairs = NLAB - p0; if (pairs > R2) pairs = R2;
    gemm_kernel<<<dim3(pairs * 2 / 128, NROWS / 128), 256, 0, stream>>>(Fb, G, 2 * p0);
    main_kernel<<<pairs, 512, 0, stream>>>(G, rs, ssorted2, pl2v, p0, part);
  }
  final_kernel<<<1, 512, 0, stream>>>(part, out);
}

// Round 9
// 130.172 us; speedup vs baseline: 1.9175x; 1.0081x over previous
//
#include <hip/hip_runtime.h>
#include <hip/hip_bf16.h>

#define NROWS 4096
#define NLAB  2048
#define NPAIR 2048
#define FMAXV 3.402823466e+38f

typedef __attribute__((ext_vector_type(8))) short short8;
typedef __attribute__((ext_vector_type(8))) unsigned short ushort8;
typedef __attribute__((ext_vector_type(4))) float f32x4;

__device__ __forceinline__ unsigned short f2bf(float x) {
  unsigned int u = __float_as_uint(x);
  unsigned int r = u + 0x7fffu + ((u >> 16) & 1u);   // RNE, no NaN in data
  return (unsigned short)(r >> 16);
}
__device__ __forceinline__ float bf2f(unsigned short h) {
  return __uint_as_float(((unsigned int)h) << 16);
}

// ---- fused prep (1024 blocks x 256): per wave = one original row:
//      rank by counting sort, then write bf16 feature row + norm at SORTED slot ----
__global__ __launch_bounds__(256) void prep_kernel(const float* __restrict__ labels,
                                                   const float* __restrict__ z1,
                                                   const float* __restrict__ z2,
                                                   unsigned short* __restrict__ Fb,
                                                   float* __restrict__ rs,
                                                   float* __restrict__ ssorted2,
                                                   int* __restrict__ pl2v) {
  __shared__ float L[NLAB];
  const int tid = threadIdx.x;
  const int lane = tid & 63, wid = tid >> 6;
  for (int t = tid; t < NLAB; t += 256) L[t] = labels[t];
  __syncthreads();
  const int i = blockIdx.x * 4 + wid;               // original row in [0,4096)
  const float a = L[i & (NLAB - 1)];
  int combo = 0;                                     // cnt | cntLE<<13
  #pragma unroll 4
  for (int jj = 0; jj < NLAB / 64; ++jj) {
    const int j = jj * 64 + lane;
    const float l = L[j];
    if (l < a) combo += 2 + (2 << 13);
    else if (l == a) combo += ((j < i) + (j + NLAB < i)) + (2 << 13);
  }
  #pragma unroll
  for (int off = 32; off > 0; off >>= 1) combo += __shfl_down(combo, off, 64);
  combo = __shfl(combo, 0, 64);                      // broadcast rank to wave
  const int cnt = combo & 8191, cle = combo >> 13;
  const float* src = (i < NLAB) ? (z1 + (size_t)i * 256)
                                : (z2 + (size_t)(i - NLAB) * 256);
  float4 v = ((const float4*)src)[lane];
  ushort4 o;
  o.x = f2bf(v.x); o.y = f2bf(v.y); o.z = f2bf(v.z); o.w = f2bf(v.w);
  ((ushort4*)Fb)[(size_t)cnt * 64 + lane] = o;
  float ss = v.x * v.x + v.y * v.y + v.z * v.z + v.w * v.w;
  #pragma unroll
  for (int off = 32; off > 0; off >>= 1) ss += __shfl_down(ss, off, 64);
  if (lane == 0) {
    rs[cnt] = ss;
    if (!(cnt & 1)) {                                // even rank: pair representative
      ssorted2[cnt >> 1] = a;
      pl2v[cnt >> 1] = (cle >> 1) - 1;               // last pair p with s2[p] <= a
    }
  }
}

// ---- G = F_sorted * F_sorted^T -> bf16. 128x128/block, 64x64/wave, deep ILP ----
__global__ __launch_bounds__(256, 2) void gemm_kernel(const unsigned short* __restrict__ Fb,
                                                      unsigned short* __restrict__ Gslab,
                                                      int row0) {
  __shared__ unsigned short tile[128][132];         // pad 132: bank-spread stores
  const int tid = threadIdx.x;
  const int lane = tid & 63, wid = tid >> 6;
  const int wm = wid >> 1, wn = wid & 1;            // 4 waves -> 2x2 of 64x64
  const int m0 = row0 + blockIdx.x * 128 + wm * 64;
  const int n0 = blockIdx.y * 128 + wn * 64;
  const int r16 = lane & 15, kg = lane >> 4;
  f32x4 acc[4][4];
  #pragma unroll
  for (int rg = 0; rg < 4; ++rg)
    #pragma unroll
    for (int cg = 0; cg < 4; ++cg) acc[rg][cg] = (f32x4){0.f, 0.f, 0.f, 0.f};
  const unsigned short* pa = Fb + (size_t)(m0 + r16) * 256 + kg * 8;
  const unsigned short* pb = Fb + (size_t)(n0 + r16) * 256 + kg * 8;
  #pragma unroll
  for (int ks = 0; ks < 8; ++ks) {                  // K = 256 = 8 x 32
    const int k0 = ks * 32;
    short8 a[4], b[4];
    #pragma unroll
    for (int rg = 0; rg < 4; ++rg) a[rg] = *(const short8*)(pa + rg * 16 * 256 + k0);
    #pragma unroll
    for (int cg = 0; cg < 4; ++cg) b[cg] = *(const short8*)(pb + cg * 16 * 256 + k0);
    #pragma unroll
    for (int rg = 0; rg < 4; ++rg)
      #pragma unroll
      for (int cg = 0; cg < 4; ++cg)
        acc[rg][cg] = __builtin_amdgcn_mfma_f32_16x16x32_bf16(a[rg], b[cg], acc[rg][cg], 0, 0, 0);
  }
  // C/D layout (m89-verified): A-row = (lane>>4)*4 + reg, B-col = lane&15
  #pragma unroll
  for (int rg = 0; rg < 4; ++rg)
    #pragma unroll
    for (int cg = 0; cg < 4; ++cg)
      #pragma unroll
      for (int rr = 0; rr < 4; ++rr)
        tile[wm * 64 + rg * 16 + kg * 4 + rr][wn * 64 + cg * 16 + r16] = f2bf(acc[rg][cg][rr]);
  __syncthreads();
  // coalesced stores: thread t covers 16B of a row; 16 threads/row; 8 passes
  const int lm = blockIdx.x * 128;
  const int gcol = blockIdx.y * 128 + (tid & 15) * 8;
  #pragma unroll
  for (int pass = 0; pass < 8; ++pass) {
    const int row = pass * 16 + (tid >> 4);
    ushort8 v = *(const ushort8*)&tile[row][(tid & 15) * 8];
    *(ushort8*)(Gslab + (size_t)(lm + row) * NROWS + gcol) = v;
  }
}

// ---- main: block = sorted pair jj (rows 2jj, 2jj+1). G sorted -> sequential
//      weights, register pair-compress + prefix, NO LDS scatter/atomics.
//      launch_bounds (512,4): 2nd arg is waves/EU; 8 capped VGPR at 64 -> spills ----
__global__ __launch_bounds__(512, 4) void main_kernel(const unsigned short* __restrict__ G,
                                                      const float* __restrict__ rs,
                                                      const float* __restrict__ ssorted2,
                                                      const int* __restrict__ pl2v,
                                                      int pair0, float2* __restrict__ part) {
  __shared__ float s2[NPAIR];                       // pair label values
  __shared__ float2 P2[NPAIR];                      // interleaved (A,B) pair prefix sums
  __shared__ float2 wsum[8];
  __shared__ float4 red[8];
  const int tid = threadIdx.x;
  const int jj = pair0 + blockIdx.x;                // pair index in [0,2048)
  const int mA = 2 * jj, mB = mA + 1;               // sorted row slots
  *(float4*)&s2[tid * 4] = ((const float4*)ssorted2)[tid];
  const float a = ssorted2[jj];
  const float ra = rs[mA], rb = rs[mB];
  const int pL2 = pl2v[jj];                         // block-uniform
  float loA = 0.f, loB = 0.f;
  float wA0, wA1, wA2, wA3, wA4, wA5, wA6, wA7;
  float wB0, wB1, wB2, wB3, wB4, wB5, wB6, wB7;
  {
    const ushort8 gva = ((const ushort8*)(G + (size_t)(2 * blockIdx.x) * NROWS))[tid];
    const ushort8 gvb = ((const ushort8*)(G + (size_t)(2 * blockIdx.x + 1) * NROWS))[tid];
    const float4 rt0 = ((const float4*)rs)[tid * 2];
    const float4 rt1 = ((const float4*)rs)[tid * 2 + 1];
    const int t = tid * 8;
    #define DOW(U, RT, WA, WB) { \
      WA = 0.f; WB = 0.f; \
      if (t + U != mA) { \
        float lo = -0.5f * __builtin_amdgcn_sqrtf(fmaxf(ra + RT - 2.f * bf2f(gva[U]), 0.f)); \
        loA += lo; WA = __expf(lo); } \
      if (t + U != mB) { \
        float lo = -0.5f * __builtin_amdgcn_sqrtf(fmaxf(rb + RT - 2.f * bf2f(gvb[U]), 0.f)); \
        loB += lo; WB = __expf(lo); } }
    DOW(0, rt0.x, wA0, wB0) DOW(1, rt0.y, wA1, wB1)
    DOW(2, rt0.z, wA2, wB2) DOW(3, rt0.w, wA3, wB3)
    DOW(4, rt1.x, wA4, wB4) DOW(5, rt1.y, wA5, wB5)
    DOW(6, rt1.z, wA6, wB6) DOW(7, rt1.w, wA7, wB7)
    #undef DOW
  }
  const float ca0 = wA0 + wA1, cb0 = wB0 + wB1;
  const float ca1 = ca0 + wA2 + wA3, cb1 = cb0 + wB2 + wB3;
  const float ca2 = ca1 + wA4 + wA5, cb2 = cb1 + wB4 + wB5;
  const float ca3 = ca2 + wA6 + wA7, cb3 = cb2 + wB6 + wB7;
  const int lane = tid & 63, wid = tid >> 6;
  float xa = ca3, xb = cb3;
  #pragma unroll
  for (int off = 1; off < 64; off <<= 1) {
    float ya = __shfl_up(xa, off, 64);
    float yb = __shfl_up(xb, off, 64);
    if (lane >= off) { xa += ya; xb += yb; }
  }
  if (lane == 63) wsum[wid] = make_float2(xa, xb);
  __syncthreads();
  float woffA = 0.f, woffB = 0.f, PtotA = 0.f, PtotB = 0.f;
  #pragma unroll
  for (int w = 0; w < 8; ++w) {
    float2 ws = wsum[w];
    PtotA += ws.x; PtotB += ws.y;
    if (w < wid) { woffA += ws.x; woffB += ws.y; }
  }
  const float exclA = woffA + xa - ca3, exclB = woffB + xb - cb3;
  const float PA0 = exclA + ca0, PA1 = exclA + ca1, PA2 = exclA + ca2, PA3 = exclA + ca3;
  const float PB0 = exclB + cb0, PB1 = exclB + cb1, PB2 = exclB + cb2, PB3 = exclB + cb3;
  const int pb = tid * 4;
  ((float4*)P2)[tid * 2]     = make_float4(PA0, PB0, PA1, PB1);
  ((float4*)P2)[tid * 2 + 1] = make_float4(PA2, PB2, PA3, PB3);
  __syncthreads();
  const float4 s2o = *(const float4*)&s2[pb];
  int rR = -1;
  int qL = -1; bool qInit = false;
  float prodA = 1.f, prodB = 1.f;
  #define STEP(U, SV, INCA, INCB, PRVA, PRVB) { \
    const int p = pb + U; \
    float WA, WB; \
    if (p <= pL2) { \
      const float v = a - SV; \
      if (rR < 0) { int lo = pL2 + 1, hi = NPAIR; \
        while (lo < hi) { int m = (lo + hi) >> 1; \
          if (s2[m] - a >= v) hi = m; else lo = m + 1; } rR = lo; } \
      else { while (rR > pL2 + 1 && s2[rR - 1] - a >= v) --rR; } \
      const float2 Pq = P2[rR - 1]; \
      WA = Pq.x - INCA; WB = Pq.y - INCB; \
    } else { \
      const float v = SV - a; \
      if (!qInit) { int lo = 0, hi = pL2 + 1; \
        while (lo < hi) { int m = (lo + hi) >> 1; \
          if (a - s2[m] >= v) lo = m + 1; else hi = m; } qL = lo - 1; qInit = true; } \
      else { while (qL >= 0 && a - s2[qL] < v) --qL; } \
      const float2 Pq = (qL >= 0) ? P2[qL] : make_float2(0.f, 0.f); \
      WA = PRVA - Pq.x; WB = PRVB - Pq.y; \
    } \
    prodA *= (PtotA - WA); prodB *= (PtotB - WB); }
  STEP(0, s2o.x, PA0, PB0, exclA, exclB)
  STEP(1, s2o.y, PA1, PB1, PA0, PB0)
  STEP(2, s2o.z, PA2, PB2, PA1, PB1)
  STEP(3, s2o.w, PA3, PB3, PA2, PB2)
  #undef STEP
  float ldA = __logf(prodA), ldB = __logf(prodB);
  #pragma unroll
  for (int off = 32; off > 0; off >>= 1) {
    loA += __shfl_down(loA, off, 64);
    loB += __shfl_down(loB, off, 64);
    ldA += __shfl_down(ldA, off, 64);
    ldB += __shfl_down(ldB, off, 64);
  }
  if (lane == 0) red[wid] = make_float4(loA, ldA, loB, ldB);
  __syncthreads();
  if (tid == 0) {
    float LA = 0.f, DA = 0.f, LB = 0.f, DB = 0.f;
    #pragma unroll
    for (int w = 0; w < 8; ++w) {
      float4 q = red[w];
      LA += q.x; DA += q.y; LB += q.z; DB += q.w;
    }
    part[mA] = make_float2(LA, 2.f * DA - __logf(PtotA));
    part[mB] = make_float2(LB, 2.f * DB - __logf(PtotB));
  }
}

__global__ __launch_bounds__(512) void final_kernel(const float2* __restrict__ part,
                                                    float* __restrict__ out) {
  const int tid = threadIdx.x;
  double L = 0.0, D = 0.0;
  for (int t = tid; t < NROWS; t += 512) {
    float2 p = part[t];
    L += (double)p.x; D += (double)p.y;
  }
  const int lane = tid & 63, wid = tid >> 6;
  #pragma unroll
  for (int off = 32; off > 0; off >>= 1) {
    L += __shfl_down(L, off, 64);
    D += __shfl_down(D, off, 64);
  }
  __shared__ double sL[8], sD[8];
  if (lane == 0) { sL[wid] = L; sD[wid] = D; }
  __syncthreads();
  if (tid == 0) {
    double Ls = 0.0, Ds = 0.0;
    #pragma unroll
    for (int w = 0; w < 8; ++w) { Ls += sL[w]; Ds += sD[w]; }
    out[0] = (float)((Ds - Ls) / 16773120.0);       // (sum log den - sum lo)/(n(n-1))
  }
}

extern "C" void kernel_launch(void* const* d_in, const int* in_sizes, int n_in,
                              void* d_out, int out_size, void* d_ws, size_t ws_size,
                              hipStream_t stream) {
  (void)in_sizes; (void)n_in; (void)out_size;
  const float* z1     = (const float*)d_in[0];
  const float* z2     = (const float*)d_in[1];
  const float* labels = (const float*)d_in[2];
  float* out = (float*)d_out;

  char* ws = (char*)d_ws;
  float2* part           = (float2*)ws;                       // 32 KB
  float*  ssorted2       = (float*)(ws + 32768);              // 8 KB
  float*  rs             = (float*)(ws + 40960);              // 16 KB (sorted norms)
  int*    pl2v           = (int*)(ws + 57344);                // 8 KB
  unsigned short* Fb     = (unsigned short*)(ws + 131072);    // 2 MB bf16 sorted feats
  const size_t G_off = (size_t)4 << 20;
  unsigned short* G = (unsigned short*)(ws + G_off);          // bf16 sorted Gram

  // pairs per slab: each pair = two 4096-col bf16 rows = 16 KB; keep 64-pair quantum
  size_t pairs_cap = (ws_size > G_off + (size_t)64 * 16384)
                         ? (ws_size - G_off) / 16384 : 64;
  int R2 = (int)((pairs_cap / 64) * 64);
  if (R2 < 64) R2 = 64;
  if (R2 > NLAB) R2 = NLAB;

  prep_kernel<<<1024, 256, 0, stream>>>(labels, z1, z2, Fb, rs, ssorted2, pl2v);
  for (int p0 = 0; p0 < NLAB; p0 += R2) {
    int pairs = NLAB - p0; if (pairs > R2) pairs = R2;
    gemm_kernel<<<dim3(pairs * 2 / 128, NROWS / 128), 256, 0, stream>>>(Fb, G, 2 * p0);
    main_kernel<<<pairs, 512, 0, stream>>>(G, rs, ssorted2, pl2v, p0, part);
  }
  final_kernel<<<1, 512, 0, stream>>>(part, out);
}